// Round 4
// baseline (553.554 us; speedup 1.0000x reference)
//
#include <hip/hip_runtime.h>
#include <math.h>

// HybridDiffusion sampling collapses analytically:
//  - In f32, C_t = max(1 + c_t, eps) == 1.0f exactly (c_t <= 2.07e-9 < half-ulp(1.0)).
//  - probs[id]   = (1-t) exactly  (w_u = c_t/31999 <= 6.5e-14 never perturbs the f32 sum)
//  - probs[MASK] = t     exactly
//  - uniform slots score <= 1.1e-6 while best of {id, MASK} scores >= 0.0217
//    -> uniform slots can NEVER win the argmax (20,000x margin).
// So z = (fl((1-t)/g[id]) >= fl(t/g[MASK])) ? id : MASK, with g = 1e-10 - log(u + 1e-10).
// Only 2 gathered floats of u needed per (b,s) row.
//
// R2 lesson: reference output is int32 (argmax). Harness reads d_out as raw
// np.int32 for int32-dtype references (error 1.19e9 == float bits of 31999.0
// read as int). Write int indices, not float.

#define V_SIZE   32000
#define MASK_ID  31999
#define SEQ_LEN  1024
#define N_ROWS   4096   // 4 * 1024

__global__ __launch_bounds__(256) void hybrid_diffusion_kernel(
        const int*   __restrict__ input_ids,   // [4, 1024]
        const float* __restrict__ t,           // [4]
        const float* __restrict__ u,           // [4, 1024, 32000]
        int*         __restrict__ out)         // [4, 1024] int32 indices
{
    int row = blockIdx.x * blockDim.x + threadIdx.x;
    if (row >= N_ROWS) return;

    const int b = row >> 10;               // row / SEQ_LEN
    const float tb  = t[b];
    const float alpha = 1.0f - tb;         // == alpha_t exactly (C_t == 1.0f in f32)

    const int id = input_ids[row];
    const float* __restrict__ urow = u + (size_t)row * V_SIZE;

    if (id == MASK_ID) {
        // Both candidates coincide; any uniform slot still can't win.
        out[row] = MASK_ID;
        return;
    }

    const float u0 = urow[id];
    const float um = urow[MASK_ID];

    // gumbel_norm, matching reference f32 arithmetic exactly
    const float g0 = 1e-10f - logf(u0 + 1e-10f);
    const float gm = 1e-10f - logf(um + 1e-10f);

    const float score_id   = alpha / g0;   // probs[id]   == (1-t) exactly
    const float score_mask = tb    / gm;   // probs[MASK] == t     exactly

    // argmax first-occurrence tie-break: id < MASK_ID, so ties go to id (>=).
    out[row] = (score_id >= score_mask) ? id : MASK_ID;
}

extern "C" void kernel_launch(void* const* d_in, const int* in_sizes, int n_in,
                              void* d_out, int out_size, void* d_ws, size_t ws_size,
                              hipStream_t stream) {
    const int*   input_ids = (const int*)  d_in[0];
    const float* t         = (const float*)d_in[1];
    const float* u         = (const float*)d_in[2];
    int*         out       = (int*)d_out;

    hybrid_diffusion_kernel<<<(N_ROWS + 255) / 256, 256, 0, stream>>>(
        input_ids, t, u, out);
}